// Round 3
// baseline (6042.181 us; speedup 1.0000x reference)
//
#include <hip/hip_runtime.h>
#include <stdint.h>

// ---------------- constants ----------------
constexpr int kB  = 64;    // batch
constexpr int kT  = 512;   // seq len
constexpr int kHD = 512;   // per-direction hidden
constexpr int kC  = 16;    // classes
constexpr int kL  = 32;    // time-chunk length
constexpr int kSTART = 14;
constexpr int kSTOP  = 15;
#define NEGV (-10000.0f)

typedef __bf16 bf16x8 __attribute__((ext_vector_type(8)));
typedef float  f32x4  __attribute__((ext_vector_type(4)));

union U16x8 { uint4 u; bf16x8 v; };

__device__ __forceinline__ unsigned short f2bf(float f) {
    union { float f; unsigned int u; } x; x.f = f;
    unsigned int u = x.u;
    u += 0x7fffu + ((u >> 16) & 1u);           // RNE
    return (unsigned short)(u >> 16);
}
__device__ __forceinline__ float bf2f(unsigned int hbits) {
    union { unsigned int u; float f; } x; x.u = hbits << 16;
    return x.f;
}

typedef __attribute__((address_space(1))) const unsigned int GASU;
typedef __attribute__((address_space(3))) unsigned int LASU;
__device__ __forceinline__ void ld_lds16(const unsigned short* g, unsigned short* l) {
    __builtin_amdgcn_global_load_lds((GASU*)g, (LASU*)l, 16, 0, 0);
}

// ---------------- permuting cast: dst row d*2048 + col*4 + gate = src row d*2048 + gate*512 + col
__global__ void k_castWx(const float* __restrict__ src, unsigned short* __restrict__ dst, int K) {
    int np = blockIdx.x;               // 0..4095 dst row
    int dd = np >> 11, r = np & 2047;
    int g = r & 3, cj = r >> 2;
    const float* s = src + ((size_t)(dd * 2048 + g * 512 + cj)) * K;
    unsigned short* d = dst + (size_t)np * K;
    for (int e = threadIdx.x * 8; e < K; e += 128 * 8) {   // block = 128
        float4 a = *(const float4*)(s + e);
        float4 b = *(const float4*)(s + e + 4);
        ushort4 lo, hi;
        lo.x = f2bf(a.x); lo.y = f2bf(a.y); lo.z = f2bf(a.z); lo.w = f2bf(a.w);
        hi.x = f2bf(b.x); hi.y = f2bf(b.y); hi.z = f2bf(b.z); hi.w = f2bf(b.w);
        *(ushort4*)(d + e) = lo; *(ushort4*)(d + e + 4) = hi;
    }
}

// ---------------- embedding gather ----------------
__global__ void k_embed(const int* __restrict__ sent, const float* __restrict__ emb,
                        unsigned short* __restrict__ X0) {
    int row = blockIdx.x;              // t*64 + b
    int t = row >> 6, b = row & 63;
    int v = sent[b * kT + t];
    const float4* src = (const float4*)(emb + (size_t)v * 512);
    float4 f = src[threadIdx.x];       // block = 128
    ushort4 o;
    o.x = f2bf(f.x); o.y = f2bf(f.y); o.z = f2bf(f.z); o.w = f2bf(f.w);
    ((ushort4*)(X0 + (size_t)row * 512))[threadIdx.x] = o;
}

// ---------------- init: h/c states, permuted fused biases, flags, lw->bf16 ----------------
__global__ void k_init(const float* __restrict__ h0, const float* __restrict__ c0,
                       const float* __restrict__ bih0, const float* __restrict__ bhh0,
                       const float* __restrict__ bih1, const float* __restrict__ bhh1,
                       const float* __restrict__ lw,
                       unsigned short* __restrict__ hcur, float* __restrict__ ccur,
                       float* __restrict__ biascat0, float* __restrict__ biascat1,
                       unsigned int* __restrict__ flags, unsigned short* __restrict__ lwb) {
    int i = blockIdx.x * blockDim.x + threadIdx.x;
    const int NS = 4 * kB * kHD;       // 131072
    if (i < NS) {
        int l = i >> 16;
        int rem = i & 65535;           // d*32768 + b*512 + j
        hcur[(size_t)l * 131072 + rem] = f2bf(h0[i]);   // parity-0 region
        ccur[i] = c0[i];
    } else if (i < NS + 8192) {
        int j2 = i - NS;
        int l = j2 >> 12;
        int n = j2 & 4095;             // src: d*2048 + g*512 + col
        int dd = n >> 11, r = n & 2047;
        int g = r >> 9, cj = r & 511;
        float v = l ? (bih1[n] + bhh1[n]) : (bih0[n] + bhh0[n]);
        int np = dd * 2048 + cj * 4 + g;   // gate-interleaved
        (l ? biascat1 : biascat0)[np] = v;
    } else if (i < NS + 8192 + 2048) {
        flags[i - NS - 8192] = 0u;
    } else if (i < NS + 8192 + 2048 + 16384) {
        int idx = i - NS - 8192 - 2048;
        lwb[idx] = f2bf(lw[idx]);
    }
}

// ---------------- standalone chunk GEMM (lead-in only) ----------------
__launch_bounds__(256, 2)
__global__ void k_gemm(const unsigned short* __restrict__ A,
                       const unsigned short* __restrict__ Bm,
                       const float* __restrict__ bias,
                       unsigned short* __restrict__ Cm,
                       int K, int afwd, int abwd) {
    const int nb = blockIdx.x & 31;
    const int mb = blockIdx.x >> 5;
    const int m0w = mb << 7;
    const int arow0 = (m0w < 2048) ? (afwd + m0w) : (abwd + (m0w - 2048));
    const int n0 = nb << 7;
    const int tid = threadIdx.x;
    const int lane = tid & 63;
    const int wave = tid >> 6;
    const int wm = wave >> 1, wn = wave & 1;
    const int l16 = lane & 15, quad = lane >> 4;
    __shared__ unsigned short As[128 * 32];
    __shared__ unsigned short Bs[128 * 32];
    const int srw = wave * 32 + (lane >> 2);
    const int sc  = lane & 3;
    unsigned short* AsW0 = As + wave * 1024;
    unsigned short* AsW1 = As + wave * 1024 + 512;
    unsigned short* BsW0 = Bs + wave * 1024;
    unsigned short* BsW1 = Bs + wave * 1024 + 512;

    f32x4 acc[4][4];
    #pragma unroll
    for (int i = 0; i < 4; ++i)
        #pragma unroll
        for (int jj = 0; jj < 4; ++jj) acc[i][jj] = (f32x4){0,0,0,0};

    const int kiters = K >> 5;
    for (int kk = 0; kk < kiters; ++kk) {
        __syncthreads();
        ld_lds16(A  + (size_t)(arow0 + srw)      * K + kk * 32 + sc * 8, AsW0);
        ld_lds16(A  + (size_t)(arow0 + srw + 16) * K + kk * 32 + sc * 8, AsW1);
        ld_lds16(Bm + (size_t)(n0 + srw)         * K + kk * 32 + sc * 8, BsW0);
        ld_lds16(Bm + (size_t)(n0 + srw + 16)    * K + kk * 32 + sc * 8, BsW1);
        __syncthreads();
        U16x8 af[4], bf[4];
        #pragma unroll
        for (int i = 0; i < 4; ++i) {
            af[i].u = *(const uint4*)(As + (wm * 64 + i * 16 + l16) * 32 + quad * 8);
            bf[i].u = *(const uint4*)(Bs + (wn * 64 + i * 16 + l16) * 32 + quad * 8);
        }
        #pragma unroll
        for (int i = 0; i < 4; ++i)
            #pragma unroll
            for (int jj = 0; jj < 4; ++jj)
                acc[i][jj] = __builtin_amdgcn_mfma_f32_16x16x32_bf16(af[i].v, bf[jj].v, acc[i][jj], 0, 0, 0);
    }
    #pragma unroll
    for (int jj = 0; jj < 4; ++jj) {
        int n = n0 + wn * 64 + jj * 16 + l16;
        float bv = bias[n];
        #pragma unroll
        for (int i = 0; i < 4; ++i) {
            int mrow = m0w + wm * 64 + i * 16 + quad * 4;
            #pragma unroll
            for (int rr = 0; rr < 4; ++rr)
                Cm[(size_t)(mrow + rr) * 4096 + n] = f2bf(acc[i][jj][rr] + bv);
        }
    }
}

// ---------------- fused: rec chunk (blocks 0..63) + next-chunk GEMM (blocks 64..255) ----
// rec step, 2 barriers:
//   Gx prefetch -> per-thread single-flag poll (flag of the one producer whose h slice
//   this thread loads) -> zbuf load -> BAR1 -> MFMA -> wave-local LDS gate transpose
//   (lgkmcnt) -> activations -> hstash (pad-35 layout) -> BAR2 ->
//     wave 0 : gather + coalesced 64B agent h-store -> own vmcnt(0) -> flag
//     waves 4..7 : coalesced hs/S output store (off flag path)
//     waves 1..3 : run ahead to next step
__launch_bounds__(512, 1)
__global__ void k_fused(const unsigned short* __restrict__ Wh,   // [2][2048][512] bf16 PERMUTED
                        const unsigned short* __restrict__ Gx,    // rec input chunk
                        unsigned short* __restrict__ hcur,
                        float* __restrict__ cc,
                        unsigned short* __restrict__ hs,          // HS
                        unsigned short* __restrict__ S,
                        unsigned int* __restrict__ flags,
                        int s0, int split,
                        const unsigned short* __restrict__ Ag,    // gemm A
                        const unsigned short* __restrict__ Wxg,   // gemm B
                        const float* __restrict__ biasg,
                        unsigned short* __restrict__ Gxout,       // gemm out (other buffer)
                        int Kg, int gfwd, int gbwd, int do_gemm) {
    __shared__ __align__(16) char smem[52928];
    const int tid = threadIdx.x;

    if (blockIdx.x < 64) {
        // ================= recurrence =================
        unsigned short* zbuf   = (unsigned short*)smem;             // 32*520*2 = 33280 B
        float*          gsAll  = (float*)(smem + 33280);            // 8 waves * 544 f32 = 17408 B
        unsigned short* hstU16 = (unsigned short*)(smem + 50688);   // 8*35 ull padded = 2240 B
        unsigned long long* hU = (unsigned long long*)(smem + 50688);
        const int blk = blockIdx.x;
        const int d  = blk >> 5;
        const int bh = (blk >> 4) & 1;
        const int wc = blk & 15;
        const int wave = tid >> 6;
        const int lane = tid & 63;
        const int l16 = lane & 15;
        const int quad = lane >> 4;
        const int r4 = lane >> 2;          // 0..15: batch row within mt-tile
        const int u  = lane & 3;           // 0..3 : hidden unit within wave
        const int col = wc * 32 + wave * 4 + u;   // hidden col 0..511
        float* gw = gsAll + wave * 544;            // [2 mt][16 rows][17] f32
        const int wcsrc = (tid & 127) >> 3;        // producer of this thread's zbuf slice

        uint4 wreg[16];
        {
            const unsigned short* wrow =
                Wh + ((size_t)d * 2048 + wc * 128 + wave * 16 + l16) * 512 + quad * 8;
            #pragma unroll
            for (int kk = 0; kk < 16; ++kk) wreg[kk] = *(const uint4*)(wrow + kk * 32);
        }
        float cst[2];
        #pragma unroll
        for (int mt = 0; mt < 2; ++mt)
            cst[mt] = cc[((size_t)d * 64 + bh * 32 + mt * 16 + r4) * 512 + col];

        unsigned int* flg = flags + (d * 2 + bh) * 256;

        for (int sl = 0; sl < kL; ++sl) {
            const int s = s0 + sl;
            const int t = d ? (kT - 1 - s) : s;
            // Gx prefetch (independent of h -> issue before the wait)
            ushort4 gx4[2];
            #pragma unroll
            for (int mt = 0; mt < 2; ++mt) {
                int b = bh * 32 + mt * 16 + r4;
                int grow = d ? (2048 + (kL - 1 - sl) * 64 + b) : (sl * 64 + b);
                gx4[mt] = *(const ushort4*)(Gx + (size_t)grow * 4096 + d * 2048 + col * 4);
            }
            // per-thread poll of the ONE producer this thread's slice depends on
            if (sl > 0) {
                unsigned tgt = (unsigned)s;
                while (__hip_atomic_load(flg + wcsrc * 16, __ATOMIC_RELAXED,
                                         __HIP_MEMORY_SCOPE_AGENT) < tgt)
                    __builtin_amdgcn_s_sleep(1);
            }
            {
                const unsigned long long* hread = (const unsigned long long*)
                    (hcur + ((size_t)((s & 1) * 2 + d) * 64 + bh * 32) * 512);
                #pragma unroll
                for (int k = 0; k < 8; ++k) {
                    int idx = tid + k * 512;
                    int r = idx >> 7, c8 = idx & 127;   // c8 = tid&127 -> one producer
                    unsigned long long v = __hip_atomic_load(hread + r * 128 + c8,
                                                             __ATOMIC_RELAXED,
                                                             __HIP_MEMORY_SCOPE_AGENT);
                    *(unsigned long long*)(zbuf + r * 520 + c8 * 4) = v;
                }
            }
            __syncthreads();                       // BAR1: zbuf complete
            f32x4 acc[2];
            acc[0] = (f32x4){0, 0, 0, 0};
            acc[1] = (f32x4){0, 0, 0, 0};
            #pragma unroll
            for (int kk = 0; kk < 16; ++kk) {
                U16x8 b; b.u = wreg[kk];
                #pragma unroll
                for (int mt = 0; mt < 2; ++mt) {
                    U16x8 a; a.u = *(const uint4*)(zbuf + (mt * 16 + l16) * 520 + kk * 32 + quad * 8);
                    acc[mt] = __builtin_amdgcn_mfma_f32_16x16x32_bf16(a.v, b.v, acc[mt], 0, 0, 0);
                }
            }
            // wave-local gate transpose: C[row=quad*4+rr][col=l16] -> (r4, u*4+g)
            #pragma unroll
            for (int mt = 0; mt < 2; ++mt)
                #pragma unroll
                for (int rr = 0; rr < 4; ++rr)
                    gw[mt * 272 + (quad * 4 + rr) * 17 + l16] = acc[mt][rr];
            asm volatile("s_waitcnt lgkmcnt(0)" ::: "memory");
            __builtin_amdgcn_sched_barrier(0);
            #pragma unroll
            for (int mt = 0; mt < 2; ++mt) {
                const float* gb = gw + mt * 272 + r4 * 17 + u * 4;
                float gi = gb[0] + bf2f(gx4[mt].x);
                float gf = gb[1] + bf2f(gx4[mt].y);
                float gg = gb[2] + bf2f(gx4[mt].z);
                float go = gb[3] + bf2f(gx4[mt].w);
                float si = 1.f / (1.f + __expf(-gi));
                float sf = 1.f / (1.f + __expf(-gf));
                float so = 1.f / (1.f + __expf(-go));
                float tg = tanhf(gg);
                float cn = sf * cst[mt] + si * tg;
                cst[mt] = cn;
                float hn = so * tanhf(cn);
                // padded hstash: ull (uu,row) at hU[uu*35+row]; this thread's uu==wave, u within
                hstU16[(wave * 35 + mt * 16 + r4) * 4 + u] = f2bf(hn);
            }
            __syncthreads();                       // BAR2: hstash complete
            if (wave == 0) {
                // gather + coalesced agent h-store (64B lines), then flag after OWN drain
                unsigned long long* hwrite = (unsigned long long*)
                    (hcur + ((size_t)(((s + 1) & 1) * 2 + d) * 64 + bh * 32) * 512);
                #pragma unroll
                for (int p = 0; p < 4; ++p) {
                    int f = p * 64 + lane;
                    int row = f >> 3, uu = f & 7;
                    unsigned long long val = hU[uu * 35 + row];
                    __hip_atomic_store(hwrite + row * 128 + wc * 8 + uu, val,
                                       __ATOMIC_RELAXED, __HIP_MEMORY_SCOPE_AGENT);
                }
                asm volatile("s_waitcnt vmcnt(0)" ::: "memory");
                __builtin_amdgcn_sched_barrier(0);
                if (lane == 0 && sl + 1 < kL)
                    __hip_atomic_store(flg + wc * 16, (unsigned)(s + 1),
                                       __ATOMIC_RELAXED, __HIP_MEMORY_SCOPE_AGENT);
            } else if (wave >= 4) {
                // time-series output, coalesced, off the flag path
                int q = tid - 256;                 // 0..255
                int r = q >> 3, uu = q & 7;
                unsigned long long val = hU[uu * 35 + r];
                int b = bh * 32 + r;
                bool toS = split && (d ? (t >= 256) : (t < 256));
                if (toS)
                    *(unsigned long long*)(S + ((size_t)t * 64 + b) * 512 + wc * 32 + uu * 4) = val;
                else
                    *(unsigned long long*)(hs + ((size_t)t * 64 + b) * 1024 + (size_t)d * 512 + wc * 32 + uu * 4) = val;
            }
            // waves 1..3: straight to next step
        }
        #pragma unroll
        for (int mt = 0; mt < 2; ++mt)
            cc[((size_t)d * 64 + bh * 32 + mt * 16 + r4) * 512 + col] = cst[mt];
    } else {
        // ================= next-chunk GEMM =================
        if (!do_gemm) return;
        const int gw = blockIdx.x - 64;            // 0..191
        const int half = tid >> 8;                 // two 128x128 tiles per WG
        const int tid2 = tid & 255;
        const int w4 = tid2 >> 6;
        const int lane = tid2 & 63;
        const int l16 = lane & 15, quad = lane >> 4;
        unsigned short* As = (unsigned short*)(smem + half * 16384);
        unsigned short* Bs = (unsigned short*)(smem + half * 16384 + 8192);
        const int srw = w4 * 32 + (lane >> 2);
        const int sc  = lane & 3;
        const int wm = w4 >> 1, wn = w4 & 1;
        unsigned short* AsW0 = As + w4 * 1024;
        unsigned short* AsW1 = As + w4 * 1024 + 512;
        unsigned short* BsW0 = Bs + w4 * 1024;
        unsigned short* BsW1 = Bs + w4 * 1024 + 512;
        const int kiters = Kg >> 5;

        for (int pp = gw; pp < 512; pp += 192) {
            const int mb = pp >> 4;
            const int nb = ((pp & 15) << 1) + half;
            const int m0w = mb << 7;
            const int arow0 = (m0w < 2048) ? (gfwd + m0w) : (gbwd + (m0w - 2048));
            const int n0 = nb << 7;
            f32x4 acc[4][4];
            #pragma unroll
            for (int i = 0; i < 4; ++i)
                #pragma unroll
                for (int jj = 0; jj < 4; ++jj) acc[i][jj] = (f32x4){0,0,0,0};
            for (int kk = 0; kk < kiters; ++kk) {
                __syncthreads();               // both halves: same trip counts
                ld_lds16(Ag  + (size_t)(arow0 + srw)      * Kg + kk * 32 + sc * 8, AsW0);
                ld_lds16(Ag  + (size_t)(arow0 + srw + 16) * Kg + kk * 32 + sc * 8, AsW1);
                ld_lds16(Wxg + (size_t)(n0 + srw)         * Kg + kk * 32 + sc * 8, BsW0);
                ld_lds16(Wxg + (size_t)(n0 + srw + 16)    * Kg + kk * 32 + sc * 8, BsW1);
                __syncthreads();
                U16x8 af[4], bf[4];
                #pragma unroll
                for (int i = 0; i < 4; ++i) {
                    af[i].u = *(const uint4*)(As + (wm * 64 + i * 16 + l16) * 32 + quad * 8);
                    bf[i].u = *(const uint4*)(Bs + (wn * 64 + i * 16 + l16) * 32 + quad * 8);
                }
                #pragma unroll
                for (int i = 0; i < 4; ++i)
                    #pragma unroll
                    for (int jj = 0; jj < 4; ++jj)
                        acc[i][jj] = __builtin_amdgcn_mfma_f32_16x16x32_bf16(af[i].v, bf[jj].v, acc[i][jj], 0, 0, 0);
            }
            #pragma unroll
            for (int jj = 0; jj < 4; ++jj) {
                int n = n0 + wn * 64 + jj * 16 + l16;
                float bv = biasg[n];
                #pragma unroll
                for (int i = 0; i < 4; ++i) {
                    int mrow = m0w + wm * 64 + i * 16 + quad * 4;
                    #pragma unroll
                    for (int rr = 0; rr < 4; ++rr)
                        Gxout[(size_t)(mrow + rr) * 4096 + n] = f2bf(acc[i][jj][rr] + bv);
                }
            }
        }
    }
}

// ---------------- final linear, MFMA version ----------------
// grid = 512 (one block per t), block = 256 (4 waves x 16 rows). K=1024 over HS/S halves.
__global__ void k_linear(const unsigned short* __restrict__ hs1,
                         const unsigned short* __restrict__ S,
                         const unsigned short* __restrict__ lwb,   // [16][1024] bf16
                         const float* __restrict__ lb,
                         float* __restrict__ feats) {
    const int t = blockIdx.x;
    const int tid = threadIdx.x;
    const int wave = tid >> 6;
    const int lane = tid & 63;
    const int l16 = lane & 15, quad = lane >> 4;
    __shared__ unsigned short lws[16 * 1032];      // padded stride: 2-way LDS reads
    {
        #pragma unroll
        for (int i = 0; i < 8; ++i) {
            int idx = tid + i * 256;               // uint4 index over 16x1024 shorts
            int n = idx >> 7, c = idx & 127;
            *(uint4*)(lws + n * 1032 + c * 8) = *(const uint4*)(lwb + n * 1024 + c * 8);
        }
    }
    __syncthreads();
    const int brow = wave * 16 + l16;              // batch row this lane's A-frag covers
    f32x4 acc = {0, 0, 0, 0};
    #pragma unroll
    for (int kk = 0; kk < 32; ++kk) {
        int k0 = kk * 32 + quad * 8;
        const unsigned short* p;
        if (kk < 16)   // fwd half: S if t<256 else HS
            p = (t < 256) ? S   + ((size_t)t * 64 + brow) * 512  + k0
                          : hs1 + ((size_t)t * 64 + brow) * 1024 + k0;
        else           // bwd half: S if t>=256 else HS
            p = (t >= 256) ? S   + ((size_t)t * 64 + brow) * 512  + (k0 - 512)
                           : hs1 + ((size_t)t * 64 + brow) * 1024 + k0;
        U16x8 a; a.u = *(const uint4*)p;
        U16x8 b; b.u = *(const uint4*)(lws + l16 * 1032 + k0);
        acc = __builtin_amdgcn_mfma_f32_16x16x32_bf16(a.v, b.v, acc, 0, 0, 0);
    }
    // C[m=quad*4+rr][n=l16]; m -> batch row, n -> class
    float bv = lb[l16];
    #pragma unroll
    for (int rr = 0; rr < 4; ++rr) {
        int b = wave * 16 + quad * 4 + rr;
        feats[(size_t)b * (kT * kC) + t * kC + l16] = acc[rr] + bv;
    }
}

// ---------------- Viterbi ----------------
__global__ void k_viterbi(const float* __restrict__ feats, const float* __restrict__ trans,
                          float* __restrict__ out) {
    int b = blockIdx.x;
    int lane = threadIdx.x;            // block = 64
    __shared__ unsigned char bp[kT * kC];
    __shared__ float fv[2][kC];
    __shared__ float tbuf[kC];
    float trow[16];
    float tstop = 0.f;
    if (lane < 16) {
        #pragma unroll
        for (int p = 0; p < 16; ++p) trow[p] = trans[lane * 16 + p];
        tstop = trans[kSTOP * 16 + lane];
        fv[0][lane] = (lane == kSTART) ? 0.f : NEGV;
    }
    __syncthreads();
    const float* fb = feats + (size_t)b * (kT * kC);
    for (int t = 0; t < kT; ++t) {
        if (lane < 16) {
            float m = -3.4e38f; int arg = 0;
            #pragma unroll
            for (int p = 0; p < 16; ++p) {
                float v = fv[t & 1][p] + trow[p];
                if (v > m) { m = v; arg = p; }   // strict >: first max = jnp.argmax
            }
            bp[t * 16 + lane] = (unsigned char)arg;
            fv[(t + 1) & 1][lane] = m + fb[t * 16 + lane];
        }
        __syncthreads();
    }
    if (lane < 16) tbuf[lane] = fv[kT & 1][lane] + tstop;
    __syncthreads();
    if (lane == 0) {
        float bm = tbuf[0]; int best = 0;
        #pragma unroll
        for (int p = 1; p < 16; ++p) if (tbuf[p] > bm) { bm = tbuf[p]; best = p; }
        out[b] = bm;
        float* path = out + kB + (size_t)b * kT;
        int tag = best;
        for (int t = kT - 1; t >= 0; --t) {
            path[t] = (float)tag;
            tag = bp[t * 16 + tag];
        }
    }
}

// ---------------- host ----------------
extern "C" void kernel_launch(void* const* d_in, const int* in_sizes, int n_in,
                              void* d_out, int out_size, void* d_ws, size_t ws_size,
                              hipStream_t stream) {
    const int*   sent = (const int*)d_in[0];
    const float* emb  = (const float*)d_in[1];
    const float* wih0 = (const float*)d_in[2];
    const float* whh0 = (const float*)d_in[3];
    const float* bih0 = (const float*)d_in[4];
    const float* bhh0 = (const float*)d_in[5];
    const float* wih1 = (const float*)d_in[6];
    const float* whh1 = (const float*)d_in[7];
    const float* bih1 = (const float*)d_in[8];
    const float* bhh1 = (const float*)d_in[9];
    const float* lw   = (const float*)d_in[10];
    const float* lb   = (const float*)d_in[11];
    const float* tr   = (const float*)d_in[12];
    const float* h0   = (const float*)d_in[13];
    const float* c0   = (const float*)d_in[14];
    float* out = (float*)d_out;

    char* ws = (char*)d_ws;
    size_t off = 0;
    auto alloc = [&](size_t bytes) -> void* {
        void* p = ws + off; off += (bytes + 255) & ~(size_t)255; return p;
    };
    // X0 (32MB) + Wx0 dead during layer-1 recurrence; S aliases X0.
    unsigned short* X0    = (unsigned short*)alloc((size_t)kT * kB * 512 * 2);       // 33.5MB
    unsigned short* Wx0   = (unsigned short*)alloc((size_t)4096 * 512 * 2);          // 4MB
    unsigned short* S     = (unsigned short*)X0;                                     // alias
    unsigned short* Wh0   = (unsigned short*)alloc((size_t)4096 * 512 * 2);          // 4MB
    unsigned short* Wx1   = (unsigned short*)alloc((size_t)4096 * 1024 * 2);         // 8MB
    unsigned short* Wh1   = (unsigned short*)alloc((size_t)4096 * 512 * 2);          // 4MB
    float*          biascat0 = (float*)alloc(4096 * 4);
    float*          biascat1 = (float*)alloc(4096 * 4);
    unsigned short* HS    = (unsigned short*)alloc((size_t)kT * kB * 1024 * 2);      // 67MB
    unsigned short* hcur  = (unsigned short*)alloc((size_t)2 * 2 * 2 * kB * kHD * 2);
    float*          ccur  = (float*)alloc((size_t)4 * kB * kHD * 4);
    float*          feats = (float*)alloc((size_t)kB * kT * kC * 4);
    unsigned int*   flags = (unsigned int*)alloc(2048 * 4);
    unsigned short* lwb   = (unsigned short*)alloc(16384 * 2);
    unsigned short* Gx0   = (unsigned short*)alloc((size_t)4096 * 4096 * 2);         // 33.5MB
    unsigned short* Gx1   = (unsigned short*)alloc((size_t)4096 * 4096 * 2);         // 33.5MB
    unsigned short* GxB[2] = {Gx0, Gx1};

    k_castWx<<<4096, 128, 0, stream>>>(wih0, Wx0, 512);
    k_castWx<<<4096, 128, 0, stream>>>(whh0, Wh0, 512);
    k_castWx<<<4096, 128, 0, stream>>>(wih1, Wx1, 1024);
    k_castWx<<<4096, 128, 0, stream>>>(whh1, Wh1, 512);
    k_init<<<(4 * kB * kHD + 8192 + 2048 + 16384 + 255) / 256, 256, 0, stream>>>(
        h0, c0, bih0, bhh0, bih1, bhh1, lw, hcur, ccur, biascat0, biascat1, flags, lwb);
    k_embed<<<kT * kB, 128, 0, stream>>>(sent, emb, X0);

    unsigned short* hcur1 = hcur + (size_t)131072;
    float*          ccur1 = ccur + (size_t)65536;

    // layer 0: lead-in GEMM, then fused rec(ch)+gemm(ch+1)
    k_gemm<<<1024, 256, 0, stream>>>(X0, Wx0, biascat0, Gx0, 512, 0, (kT - kL) * 64);
    for (int ch = 0; ch < 16; ++ch) {
        int s0n = (ch + 1) * kL;
        k_fused<<<256, 512, 0, stream>>>(Wh0, GxB[ch & 1], hcur, ccur, HS, S, flags, ch * kL, 0,
                                         X0, Wx0, biascat0, GxB[(ch + 1) & 1], 512,
                                         s0n * 64, (kT - kL - s0n) * 64, ch < 15);
    }
    // layer 1: lead-in GEMM (after l0 fully done), then fused
    k_gemm<<<1024, 256, 0, stream>>>(HS, Wx1, biascat1, Gx0, 1024, 0, (kT - kL) * 64);
    for (int ch = 0; ch < 16; ++ch) {
        int s0n = (ch + 1) * kL;
        k_fused<<<256, 512, 0, stream>>>(Wh1, GxB[ch & 1], hcur1, ccur1, HS, S, flags + 1024, ch * kL, 1,
                                         HS, Wx1, biascat1, GxB[(ch + 1) & 1], 1024,
                                         s0n * 64, (kT - kL - s0n) * 64, ch < 15);
    }

    k_linear<<<kT, 256, 0, stream>>>(HS, S, lwb, lb, feats);
    k_viterbi<<<kB, 64, 0, stream>>>(feats, tr, out);
}

// Round 4
// 5068.791 us; speedup vs baseline: 1.1920x; 1.1920x over previous
//
#include <hip/hip_runtime.h>
#include <stdint.h>

// ---------------- constants ----------------
constexpr int kB  = 64;    // batch
constexpr int kT  = 512;   // seq len
constexpr int kHD = 512;   // per-direction hidden
constexpr int kC  = 16;    // classes
constexpr int kL  = 32;    // time-chunk length
constexpr int kSTART = 14;
constexpr int kSTOP  = 15;
#define NEGV (-10000.0f)

typedef __bf16 bf16x8 __attribute__((ext_vector_type(8)));
typedef float  f32x4  __attribute__((ext_vector_type(4)));

union U16x8 { uint4 u; bf16x8 v; };

__device__ __forceinline__ unsigned short f2bf(float f) {
    union { float f; unsigned int u; } x; x.f = f;
    unsigned int u = x.u;
    u += 0x7fffu + ((u >> 16) & 1u);           // RNE
    return (unsigned short)(u >> 16);
}
__device__ __forceinline__ float bf2f(unsigned int hbits) {
    union { unsigned int u; float f; } x; x.u = hbits << 16;
    return x.f;
}
// fast sigmoid / tanh: v_rcp_f32 based (error ~1e-7, far below bf16 LSB)
__device__ __forceinline__ float fsig(float x) {
    return __builtin_amdgcn_rcpf(1.f + __expf(-x));
}
__device__ __forceinline__ float ftanh(float x) {
    float e = __expf(2.f * x);                 // inf for large x -> rcp=0 -> 1
    return 1.f - 2.f * __builtin_amdgcn_rcpf(e + 1.f);
}

typedef __attribute__((address_space(1))) const unsigned int GASU;
typedef __attribute__((address_space(3))) unsigned int LASU;
__device__ __forceinline__ void ld_lds16(const unsigned short* g, unsigned short* l) {
    __builtin_amdgcn_global_load_lds((GASU*)g, (LASU*)l, 16, 0, 0);
}

// ---------------- permuting cast: dst row d*2048 + col*4 + gate = src row d*2048 + gate*512 + col
__global__ void k_castWx(const float* __restrict__ src, unsigned short* __restrict__ dst, int K) {
    int np = blockIdx.x;               // 0..4095 dst row
    int dd = np >> 11, r = np & 2047;
    int g = r & 3, cj = r >> 2;
    const float* s = src + ((size_t)(dd * 2048 + g * 512 + cj)) * K;
    unsigned short* d = dst + (size_t)np * K;
    for (int e = threadIdx.x * 8; e < K; e += 128 * 8) {   // block = 128
        float4 a = *(const float4*)(s + e);
        float4 b = *(const float4*)(s + e + 4);
        ushort4 lo, hi;
        lo.x = f2bf(a.x); lo.y = f2bf(a.y); lo.z = f2bf(a.z); lo.w = f2bf(a.w);
        hi.x = f2bf(b.x); hi.y = f2bf(b.y); hi.z = f2bf(b.z); hi.w = f2bf(b.w);
        *(ushort4*)(d + e) = lo; *(ushort4*)(d + e + 4) = hi;
    }
}

// ---------------- embedding gather ----------------
__global__ void k_embed(const int* __restrict__ sent, const float* __restrict__ emb,
                        unsigned short* __restrict__ X0) {
    int row = blockIdx.x;              // t*64 + b
    int t = row >> 6, b = row & 63;
    int v = sent[b * kT + t];
    const float4* src = (const float4*)(emb + (size_t)v * 512);
    float4 f = src[threadIdx.x];       // block = 128
    ushort4 o;
    o.x = f2bf(f.x); o.y = f2bf(f.y); o.z = f2bf(f.z); o.w = f2bf(f.w);
    ((ushort4*)(X0 + (size_t)row * 512))[threadIdx.x] = o;
}

// ---------------- init: h/c states, permuted fused biases, flags, lw->bf16 ----------------
__global__ void k_init(const float* __restrict__ h0, const float* __restrict__ c0,
                       const float* __restrict__ bih0, const float* __restrict__ bhh0,
                       const float* __restrict__ bih1, const float* __restrict__ bhh1,
                       const float* __restrict__ lw,
                       unsigned short* __restrict__ hcur, float* __restrict__ ccur,
                       float* __restrict__ biascat0, float* __restrict__ biascat1,
                       unsigned int* __restrict__ flags, unsigned short* __restrict__ lwb) {
    int i = blockIdx.x * blockDim.x + threadIdx.x;
    const int NS = 4 * kB * kHD;       // 131072
    if (i < NS) {
        int l = i >> 16;
        int rem = i & 65535;           // d*32768 + b*512 + j
        hcur[(size_t)l * 131072 + rem] = f2bf(h0[i]);   // parity-0 region
        ccur[i] = c0[i];
    } else if (i < NS + 8192) {
        int j2 = i - NS;
        int l = j2 >> 12;
        int n = j2 & 4095;             // src: d*2048 + g*512 + col
        int dd = n >> 11, r = n & 2047;
        int g = r >> 9, cj = r & 511;
        float v = l ? (bih1[n] + bhh1[n]) : (bih0[n] + bhh0[n]);
        int np = dd * 2048 + cj * 4 + g;   // gate-interleaved
        (l ? biascat1 : biascat0)[np] = v;
    } else if (i < NS + 8192 + 2048) {
        flags[i - NS - 8192] = 0u;
    } else if (i < NS + 8192 + 2048 + 16384) {
        int idx = i - NS - 8192 - 2048;
        lwb[idx] = f2bf(lw[idx]);
    }
}

// ---------------- standalone chunk GEMM (lead-in only) ----------------
__launch_bounds__(256, 2)
__global__ void k_gemm(const unsigned short* __restrict__ A,
                       const unsigned short* __restrict__ Bm,
                       const float* __restrict__ bias,
                       unsigned short* __restrict__ Cm,
                       int K, int afwd, int abwd) {
    const int nb = blockIdx.x & 31;
    const int mb = blockIdx.x >> 5;
    const int m0w = mb << 7;
    const int arow0 = (m0w < 2048) ? (afwd + m0w) : (abwd + (m0w - 2048));
    const int n0 = nb << 7;
    const int tid = threadIdx.x;
    const int lane = tid & 63;
    const int wave = tid >> 6;
    const int wm = wave >> 1, wn = wave & 1;
    const int l16 = lane & 15, quad = lane >> 4;
    __shared__ unsigned short As[128 * 32];
    __shared__ unsigned short Bs[128 * 32];
    const int srw = wave * 32 + (lane >> 2);
    const int sc  = lane & 3;
    unsigned short* AsW0 = As + wave * 1024;
    unsigned short* AsW1 = As + wave * 1024 + 512;
    unsigned short* BsW0 = Bs + wave * 1024;
    unsigned short* BsW1 = Bs + wave * 1024 + 512;

    f32x4 acc[4][4];
    #pragma unroll
    for (int i = 0; i < 4; ++i)
        #pragma unroll
        for (int jj = 0; jj < 4; ++jj) acc[i][jj] = (f32x4){0,0,0,0};

    const int kiters = K >> 5;
    for (int kk = 0; kk < kiters; ++kk) {
        __syncthreads();
        ld_lds16(A  + (size_t)(arow0 + srw)      * K + kk * 32 + sc * 8, AsW0);
        ld_lds16(A  + (size_t)(arow0 + srw + 16) * K + kk * 32 + sc * 8, AsW1);
        ld_lds16(Bm + (size_t)(n0 + srw)         * K + kk * 32 + sc * 8, BsW0);
        ld_lds16(Bm + (size_t)(n0 + srw + 16)    * K + kk * 32 + sc * 8, BsW1);
        __syncthreads();
        U16x8 af[4], bf[4];
        #pragma unroll
        for (int i = 0; i < 4; ++i) {
            af[i].u = *(const uint4*)(As + (wm * 64 + i * 16 + l16) * 32 + quad * 8);
            bf[i].u = *(const uint4*)(Bs + (wn * 64 + i * 16 + l16) * 32 + quad * 8);
        }
        #pragma unroll
        for (int i = 0; i < 4; ++i)
            #pragma unroll
            for (int jj = 0; jj < 4; ++jj)
                acc[i][jj] = __builtin_amdgcn_mfma_f32_16x16x32_bf16(af[i].v, bf[jj].v, acc[i][jj], 0, 0, 0);
    }
    #pragma unroll
    for (int jj = 0; jj < 4; ++jj) {
        int n = n0 + wn * 64 + jj * 16 + l16;
        float bv = bias[n];
        #pragma unroll
        for (int i = 0; i < 4; ++i) {
            int mrow = m0w + wm * 64 + i * 16 + quad * 4;
            #pragma unroll
            for (int rr = 0; rr < 4; ++rr)
                Cm[(size_t)(mrow + rr) * 4096 + n] = f2bf(acc[i][jj][rr] + bv);
        }
    }
}

// ---------------- fused: rec chunk (blocks 0..63) + next-chunk GEMM (blocks 64..255) ----
// rec step (r0 structure + wave-local transpose + deferred hs/S + fast activations):
//   Gx prefetch -> [wave0 lane<16 poll 16 flags; WAIT-BAR] -> zbuf load -> BAR1 ->
//   MFMA -> wave-local LDS gate transpose (lgkmcnt) -> activations -> hstash ->
//   BAR2 -> tid<256: coalesced 64B agent h-store -> BAR3 (drains h only) ->
//   tid0: flag   ||   tid>=256: hs/S stores (off the flag path, drain next step)
__launch_bounds__(512, 1)
__global__ void k_fused(const unsigned short* __restrict__ Wh,   // [2][2048][512] bf16 PERMUTED
                        const unsigned short* __restrict__ Gx,    // rec input chunk
                        unsigned short* __restrict__ hcur,
                        float* __restrict__ cc,
                        unsigned short* __restrict__ hs,          // HS
                        unsigned short* __restrict__ S,
                        unsigned int* __restrict__ flags,
                        int s0, int split,
                        const unsigned short* __restrict__ Ag,    // gemm A
                        const unsigned short* __restrict__ Wxg,   // gemm B
                        const float* __restrict__ biasg,
                        unsigned short* __restrict__ Gxout,       // gemm out (other buffer)
                        int Kg, int gfwd, int gbwd, int do_gemm) {
    __shared__ __align__(16) char smem[52928];
    const int tid = threadIdx.x;

    if (blockIdx.x < 64) {
        // ================= recurrence =================
        unsigned short* zbuf   = (unsigned short*)smem;             // 32*520*2 = 33280 B
        float*          gsAll  = (float*)(smem + 33280);            // 8 waves * 544 f32 = 17408 B
        unsigned short* hstU16 = (unsigned short*)(smem + 50688);   // 8*35 ull padded = 2240 B
        unsigned long long* hU = (unsigned long long*)(smem + 50688);
        const int blk = blockIdx.x;
        const int d  = blk >> 5;
        const int bh = (blk >> 4) & 1;
        const int wc = blk & 15;
        const int wave = tid >> 6;
        const int lane = tid & 63;
        const int l16 = lane & 15;
        const int quad = lane >> 4;
        const int r4 = lane >> 2;          // 0..15: batch row within mt-tile
        const int u  = lane & 3;           // 0..3 : hidden unit within wave
        const int col = wc * 32 + wave * 4 + u;   // hidden col 0..511
        float* gw = gsAll + wave * 544;            // [2 mt][16 rows][17] f32

        uint4 wreg[16];
        {
            const unsigned short* wrow =
                Wh + ((size_t)d * 2048 + wc * 128 + wave * 16 + l16) * 512 + quad * 8;
            #pragma unroll
            for (int kk = 0; kk < 16; ++kk) wreg[kk] = *(const uint4*)(wrow + kk * 32);
        }
        float cst[2];
        #pragma unroll
        for (int mt = 0; mt < 2; ++mt)
            cst[mt] = cc[((size_t)d * 64 + bh * 32 + mt * 16 + r4) * 512 + col];

        unsigned int* flg = flags + (d * 2 + bh) * 256;

        for (int sl = 0; sl < kL; ++sl) {
            const int s = s0 + sl;
            const int t = d ? (kT - 1 - s) : s;
            // Gx prefetch (independent of h -> issue before the wait)
            ushort4 gx4[2];
            #pragma unroll
            for (int mt = 0; mt < 2; ++mt) {
                int b = bh * 32 + mt * 16 + r4;
                int grow = d ? (2048 + (kL - 1 - sl) * 64 + b) : (sl * 64 + b);
                gx4[mt] = *(const ushort4*)(Gx + (size_t)grow * 4096 + d * 2048 + col * 4);
            }
            // minimal-poller scheme: wave0's 16 lanes poll the 16 producer flags
            if (sl > 0) {
                if (wave == 0 && lane < 16) {
                    unsigned tgt = (unsigned)s;
                    while (__hip_atomic_load(flg + lane * 16, __ATOMIC_RELAXED,
                                             __HIP_MEMORY_SCOPE_AGENT) < tgt)
                        __builtin_amdgcn_s_sleep(1);
                }
                __syncthreads();               // WAIT-BAR
            }
            {
                const unsigned long long* hread = (const unsigned long long*)
                    (hcur + ((size_t)((s & 1) * 2 + d) * 64 + bh * 32) * 512);
                #pragma unroll
                for (int k = 0; k < 8; ++k) {
                    int idx = tid + k * 512;
                    int r = idx >> 7, c8 = idx & 127;
                    unsigned long long v = __hip_atomic_load(hread + r * 128 + c8,
                                                             __ATOMIC_RELAXED,
                                                             __HIP_MEMORY_SCOPE_AGENT);
                    *(unsigned long long*)(zbuf + r * 520 + c8 * 4) = v;
                }
            }
            __syncthreads();                       // BAR1: zbuf complete
            f32x4 acc[2];
            acc[0] = (f32x4){0, 0, 0, 0};
            acc[1] = (f32x4){0, 0, 0, 0};
            #pragma unroll
            for (int kk = 0; kk < 16; ++kk) {
                U16x8 b; b.u = wreg[kk];
                #pragma unroll
                for (int mt = 0; mt < 2; ++mt) {
                    U16x8 a; a.u = *(const uint4*)(zbuf + (mt * 16 + l16) * 520 + kk * 32 + quad * 8);
                    acc[mt] = __builtin_amdgcn_mfma_f32_16x16x32_bf16(a.v, b.v, acc[mt], 0, 0, 0);
                }
            }
            // wave-local gate transpose: C[row=quad*4+rr][col=l16] -> (r4, u*4+g)
            #pragma unroll
            for (int mt = 0; mt < 2; ++mt)
                #pragma unroll
                for (int rr = 0; rr < 4; ++rr)
                    gw[mt * 272 + (quad * 4 + rr) * 17 + l16] = acc[mt][rr];
            asm volatile("s_waitcnt lgkmcnt(0)" ::: "memory");
            __builtin_amdgcn_sched_barrier(0);
            #pragma unroll
            for (int mt = 0; mt < 2; ++mt) {
                const float* gb = gw + mt * 272 + r4 * 17 + u * 4;
                float gi = gb[0] + bf2f(gx4[mt].x);
                float gf = gb[1] + bf2f(gx4[mt].y);
                float gg = gb[2] + bf2f(gx4[mt].z);
                float go = gb[3] + bf2f(gx4[mt].w);
                float si = fsig(gi);
                float sf = fsig(gf);
                float so = fsig(go);
                float tg = ftanh(gg);
                float cn = sf * cst[mt] + si * tg;
                cst[mt] = cn;
                float hn = so * ftanh(cn);
                // padded hstash: ull (wave,row) at hU[wave*35+row]
                hstU16[(wave * 35 + mt * 16 + r4) * 4 + u] = f2bf(hn);
            }
            __syncthreads();                       // BAR2: hstash complete
            if (tid < 256) {
                // distributed coalesced agent h-store: 8 threads = one 64B line
                int r = tid >> 3, uu = tid & 7;
                unsigned long long val = hU[uu * 35 + r];
                unsigned long long* hwrite = (unsigned long long*)
                    (hcur + ((size_t)(((s + 1) & 1) * 2 + d) * 64 + bh * 32) * 512);
                __hip_atomic_store(hwrite + r * 128 + wc * 8 + uu, val,
                                   __ATOMIC_RELAXED, __HIP_MEMORY_SCOPE_AGENT);
            }
            __syncthreads();                       // BAR3: drains h stores only
            if (tid == 0 && sl + 1 < kL)
                __hip_atomic_store(flg + wc * 16, (unsigned)(s + 1),
                                   __ATOMIC_RELAXED, __HIP_MEMORY_SCOPE_AGENT);
            if (tid >= 256) {
                // time-series output AFTER the flag: off the inter-block critical path
                int q = tid - 256;                 // 0..255
                int r = q >> 3, uu = q & 7;
                unsigned long long val = hU[uu * 35 + r];
                int b = bh * 32 + r;
                bool toS = split && (d ? (t >= 256) : (t < 256));
                if (toS)
                    *(unsigned long long*)(S + ((size_t)t * 64 + b) * 512 + wc * 32 + uu * 4) = val;
                else
                    *(unsigned long long*)(hs + ((size_t)t * 64 + b) * 1024 + (size_t)d * 512 + wc * 32 + uu * 4) = val;
            }
        }
        #pragma unroll
        for (int mt = 0; mt < 2; ++mt)
            cc[((size_t)d * 64 + bh * 32 + mt * 16 + r4) * 512 + col] = cst[mt];
    } else {
        // ================= next-chunk GEMM =================
        if (!do_gemm) return;
        const int gw = blockIdx.x - 64;            // 0..191
        const int half = tid >> 8;                 // two 128x128 tiles per WG
        const int tid2 = tid & 255;
        const int w4 = tid2 >> 6;
        const int lane = tid2 & 63;
        const int l16 = lane & 15, quad = lane >> 4;
        unsigned short* As = (unsigned short*)(smem + half * 16384);
        unsigned short* Bs = (unsigned short*)(smem + half * 16384 + 8192);
        const int srw = w4 * 32 + (lane >> 2);
        const int sc  = lane & 3;
        const int wm = w4 >> 1, wn = w4 & 1;
        unsigned short* AsW0 = As + w4 * 1024;
        unsigned short* AsW1 = As + w4 * 1024 + 512;
        unsigned short* BsW0 = Bs + w4 * 1024;
        unsigned short* BsW1 = Bs + w4 * 1024 + 512;
        const int kiters = Kg >> 5;

        for (int pp = gw; pp < 512; pp += 192) {
            const int mb = pp >> 4;
            const int nb = ((pp & 15) << 1) + half;
            const int m0w = mb << 7;
            const int arow0 = (m0w < 2048) ? (gfwd + m0w) : (gbwd + (m0w - 2048));
            const int n0 = nb << 7;
            f32x4 acc[4][4];
            #pragma unroll
            for (int i = 0; i < 4; ++i)
                #pragma unroll
                for (int jj = 0; jj < 4; ++jj) acc[i][jj] = (f32x4){0,0,0,0};
            for (int kk = 0; kk < kiters; ++kk) {
                __syncthreads();               // both halves: same trip counts
                ld_lds16(Ag  + (size_t)(arow0 + srw)      * Kg + kk * 32 + sc * 8, AsW0);
                ld_lds16(Ag  + (size_t)(arow0 + srw + 16) * Kg + kk * 32 + sc * 8, AsW1);
                ld_lds16(Wxg + (size_t)(n0 + srw)         * Kg + kk * 32 + sc * 8, BsW0);
                ld_lds16(Wxg + (size_t)(n0 + srw + 16)    * Kg + kk * 32 + sc * 8, BsW1);
                __syncthreads();
                U16x8 af[4], bf[4];
                #pragma unroll
                for (int i = 0; i < 4; ++i) {
                    af[i].u = *(const uint4*)(As + (wm * 64 + i * 16 + l16) * 32 + quad * 8);
                    bf[i].u = *(const uint4*)(Bs + (wn * 64 + i * 16 + l16) * 32 + quad * 8);
                }
                #pragma unroll
                for (int i = 0; i < 4; ++i)
                    #pragma unroll
                    for (int jj = 0; jj < 4; ++jj)
                        acc[i][jj] = __builtin_amdgcn_mfma_f32_16x16x32_bf16(af[i].v, bf[jj].v, acc[i][jj], 0, 0, 0);
            }
            #pragma unroll
            for (int jj = 0; jj < 4; ++jj) {
                int n = n0 + wn * 64 + jj * 16 + l16;
                float bv = biasg[n];
                #pragma unroll
                for (int i = 0; i < 4; ++i) {
                    int mrow = m0w + wm * 64 + i * 16 + quad * 4;
                    #pragma unroll
                    for (int rr = 0; rr < 4; ++rr)
                        Gxout[(size_t)(mrow + rr) * 4096 + n] = f2bf(acc[i][jj][rr] + bv);
                }
            }
        }
    }
}

// ---------------- final linear, MFMA version ----------------
// grid = 512 (one block per t), block = 256 (4 waves x 16 rows). K=1024 over HS/S halves.
__global__ void k_linear(const unsigned short* __restrict__ hs1,
                         const unsigned short* __restrict__ S,
                         const unsigned short* __restrict__ lwb,   // [16][1024] bf16
                         const float* __restrict__ lb,
                         float* __restrict__ feats) {
    const int t = blockIdx.x;
    const int tid = threadIdx.x;
    const int wave = tid >> 6;
    const int lane = tid & 63;
    const int l16 = lane & 15, quad = lane >> 4;
    __shared__ unsigned short lws[16 * 1032];      // padded stride: 2-way LDS reads
    {
        #pragma unroll
        for (int i = 0; i < 8; ++i) {
            int idx = tid + i * 256;               // uint4 index over 16x1024 shorts
            int n = idx >> 7, c = idx & 127;
            *(uint4*)(lws + n * 1032 + c * 8) = *(const uint4*)(lwb + n * 1024 + c * 8);
        }
    }
    __syncthreads();
    const int brow = wave * 16 + l16;              // batch row this lane's A-frag covers
    f32x4 acc = {0, 0, 0, 0};
    #pragma unroll
    for (int kk = 0; kk < 32; ++kk) {
        int k0 = kk * 32 + quad * 8;
        const unsigned short* p;
        if (kk < 16)   // fwd half: S if t<256 else HS
            p = (t < 256) ? S   + ((size_t)t * 64 + brow) * 512  + k0
                          : hs1 + ((size_t)t * 64 + brow) * 1024 + k0;
        else           // bwd half: S if t>=256 else HS
            p = (t >= 256) ? S   + ((size_t)t * 64 + brow) * 512  + (k0 - 512)
                           : hs1 + ((size_t)t * 64 + brow) * 1024 + k0;
        U16x8 a; a.u = *(const uint4*)p;
        U16x8 b; b.u = *(const uint4*)(lws + l16 * 1032 + k0);
        acc = __builtin_amdgcn_mfma_f32_16x16x32_bf16(a.v, b.v, acc, 0, 0, 0);
    }
    // C[m=quad*4+rr][n=l16]; m -> batch row, n -> class
    float bv = lb[l16];
    #pragma unroll
    for (int rr = 0; rr < 4; ++rr) {
        int b = wave * 16 + quad * 4 + rr;
        feats[(size_t)b * (kT * kC) + t * kC + l16] = acc[rr] + bv;
    }
}

// ---------------- Viterbi ----------------
__global__ void k_viterbi(const float* __restrict__ feats, const float* __restrict__ trans,
                          float* __restrict__ out) {
    int b = blockIdx.x;
    int lane = threadIdx.x;            // block = 64
    __shared__ unsigned char bp[kT * kC];
    __shared__ float fv[2][kC];
    __shared__ float tbuf[kC];
    float trow[16];
    float tstop = 0.f;
    if (lane < 16) {
        #pragma unroll
        for (int p = 0; p < 16; ++p) trow[p] = trans[lane * 16 + p];
        tstop = trans[kSTOP * 16 + lane];
        fv[0][lane] = (lane == kSTART) ? 0.f : NEGV;
    }
    __syncthreads();
    const float* fb = feats + (size_t)b * (kT * kC);
    for (int t = 0; t < kT; ++t) {
        if (lane < 16) {
            float m = -3.4e38f; int arg = 0;
            #pragma unroll
            for (int p = 0; p < 16; ++p) {
                float v = fv[t & 1][p] + trow[p];
                if (v > m) { m = v; arg = p; }   // strict >: first max = jnp.argmax
            }
            bp[t * 16 + lane] = (unsigned char)arg;
            fv[(t + 1) & 1][lane] = m + fb[t * 16 + lane];
        }
        __syncthreads();
    }
    if (lane < 16) tbuf[lane] = fv[kT & 1][lane] + tstop;
    __syncthreads();
    if (lane == 0) {
        float bm = tbuf[0]; int best = 0;
        #pragma unroll
        for (int p = 1; p < 16; ++p) if (tbuf[p] > bm) { bm = tbuf[p]; best = p; }
        out[b] = bm;
        float* path = out + kB + (size_t)b * kT;
        int tag = best;
        for (int t = kT - 1; t >= 0; --t) {
            path[t] = (float)tag;
            tag = bp[t * 16 + tag];
        }
    }
}

// ---------------- host ----------------
extern "C" void kernel_launch(void* const* d_in, const int* in_sizes, int n_in,
                              void* d_out, int out_size, void* d_ws, size_t ws_size,
                              hipStream_t stream) {
    const int*   sent = (const int*)d_in[0];
    const float* emb  = (const float*)d_in[1];
    const float* wih0 = (const float*)d_in[2];
    const float* whh0 = (const float*)d_in[3];
    const float* bih0 = (const float*)d_in[4];
    const float* bhh0 = (const float*)d_in[5];
    const float* wih1 = (const float*)d_in[6];
    const float* whh1 = (const float*)d_in[7];
    const float* bih1 = (const float*)d_in[8];
    const float* bhh1 = (const float*)d_in[9];
    const float* lw   = (const float*)d_in[10];
    const float* lb   = (const float*)d_in[11];
    const float* tr   = (const float*)d_in[12];
    const float* h0   = (const float*)d_in[13];
    const float* c0   = (const float*)d_in[14];
    float* out = (float*)d_out;

    char* ws = (char*)d_ws;
    size_t off = 0;
    auto alloc = [&](size_t bytes) -> void* {
        void* p = ws + off; off += (bytes + 255) & ~(size_t)255; return p;
    };
    // X0 (32MB) + Wx0 dead during layer-1 recurrence; S aliases X0.
    unsigned short* X0    = (unsigned short*)alloc((size_t)kT * kB * 512 * 2);       // 33.5MB
    unsigned short* Wx0   = (unsigned short*)alloc((size_t)4096 * 512 * 2);          // 4MB
    unsigned short* S     = (unsigned short*)X0;                                     // alias
    unsigned short* Wh0   = (unsigned short*)alloc((size_t)4096 * 512 * 2);          // 4MB
    unsigned short* Wx1   = (unsigned short*)alloc((size_t)4096 * 1024 * 2);         // 8MB
    unsigned short* Wh1   = (unsigned short*)alloc((size_t)4096 * 512 * 2);          // 4MB
    float*          biascat0 = (float*)alloc(4096 * 4);
    float*          biascat1 = (float*)alloc(4096 * 4);
    unsigned short* HS    = (unsigned short*)alloc((size_t)kT * kB * 1024 * 2);      // 67MB
    unsigned short* hcur  = (unsigned short*)alloc((size_t)2 * 2 * 2 * kB * kHD * 2);
    float*          ccur  = (float*)alloc((size_t)4 * kB * kHD * 4);
    float*          feats = (float*)alloc((size_t)kB * kT * kC * 4);
    unsigned int*   flags = (unsigned int*)alloc(2048 * 4);
    unsigned short* lwb   = (unsigned short*)alloc(16384 * 2);
    unsigned short* Gx0   = (unsigned short*)alloc((size_t)4096 * 4096 * 2);         // 33.5MB
    unsigned short* Gx1   = (unsigned short*)alloc((size_t)4096 * 4096 * 2);         // 33.5MB
    unsigned short* GxB[2] = {Gx0, Gx1};

    k_castWx<<<4096, 128, 0, stream>>>(wih0, Wx0, 512);
    k_castWx<<<4096, 128, 0, stream>>>(whh0, Wh0, 512);
    k_castWx<<<4096, 128, 0, stream>>>(wih1, Wx1, 1024);
    k_castWx<<<4096, 128, 0, stream>>>(whh1, Wh1, 512);
    k_init<<<(4 * kB * kHD + 8192 + 2048 + 16384 + 255) / 256, 256, 0, stream>>>(
        h0, c0, bih0, bhh0, bih1, bhh1, lw, hcur, ccur, biascat0, biascat1, flags, lwb);
    k_embed<<<kT * kB, 128, 0, stream>>>(sent, emb, X0);

    unsigned short* hcur1 = hcur + (size_t)131072;
    float*          ccur1 = ccur + (size_t)65536;

    // layer 0: lead-in GEMM, then fused rec(ch)+gemm(ch+1)
    k_gemm<<<1024, 256, 0, stream>>>(X0, Wx0, biascat0, Gx0, 512, 0, (kT - kL) * 64);
    for (int ch = 0; ch < 16; ++ch) {
        int s0n = (ch + 1) * kL;
        k_fused<<<256, 512, 0, stream>>>(Wh0, GxB[ch & 1], hcur, ccur, HS, S, flags, ch * kL, 0,
                                         X0, Wx0, biascat0, GxB[(ch + 1) & 1], 512,
                                         s0n * 64, (kT - kL - s0n) * 64, ch < 15);
    }
    // layer 1: lead-in GEMM (after l0 fully done), then fused
    k_gemm<<<1024, 256, 0, stream>>>(HS, Wx1, biascat1, Gx0, 1024, 0, (kT - kL) * 64);
    for (int ch = 0; ch < 16; ++ch) {
        int s0n = (ch + 1) * kL;
        k_fused<<<256, 512, 0, stream>>>(Wh1, GxB[ch & 1], hcur1, ccur1, HS, S, flags + 1024, ch * kL, 1,
                                         HS, Wx1, biascat1, GxB[(ch + 1) & 1], 1024,
                                         s0n * 64, (kT - kL - s0n) * 64, ch < 15);
    }

    k_linear<<<kT, 256, 0, stream>>>(HS, S, lwb, lb, feats);
    k_viterbi<<<kB, 64, 0, stream>>>(feats, tr, out);
}

// Round 5
// 4673.237 us; speedup vs baseline: 1.2929x; 1.0846x over previous
//
#include <hip/hip_runtime.h>
#include <stdint.h>

// ---------------- constants ----------------
constexpr int kB  = 64;    // batch
constexpr int kT  = 512;   // seq len
constexpr int kHD = 512;   // per-direction hidden
constexpr int kC  = 16;    // classes
constexpr int kL  = 32;    // time-chunk length
constexpr int kSTART = 14;
constexpr int kSTOP  = 15;
#define NEGV (-10000.0f)

typedef __bf16 bf16x8 __attribute__((ext_vector_type(8)));
typedef float  f32x4  __attribute__((ext_vector_type(4)));

union U16x8 { uint4 u; bf16x8 v; };

__device__ __forceinline__ unsigned short f2bf(float f) {
    union { float f; unsigned int u; } x; x.f = f;
    unsigned int u = x.u;
    u += 0x7fffu + ((u >> 16) & 1u);           // RNE
    return (unsigned short)(u >> 16);
}
__device__ __forceinline__ float bf2f(unsigned int hbits) {
    union { unsigned int u; float f; } x; x.u = hbits << 16;
    return x.f;
}
// fast sigmoid / tanh: v_rcp_f32 based (error ~1e-7, far below bf16 LSB)
__device__ __forceinline__ float fsig(float x) {
    return __builtin_amdgcn_rcpf(1.f + __expf(-x));
}
__device__ __forceinline__ float ftanh(float x) {
    float e = __expf(2.f * x);                 // inf for large x -> rcp=0 -> 1
    return 1.f - 2.f * __builtin_amdgcn_rcpf(e + 1.f);
}

typedef __attribute__((address_space(1))) const unsigned int GASU;
typedef __attribute__((address_space(3))) unsigned int LASU;
__device__ __forceinline__ void ld_lds16(const unsigned short* g, unsigned short* l) {
    __builtin_amdgcn_global_load_lds((GASU*)g, (LASU*)l, 16, 0, 0);
}

// Exchange buffer X (per layer): [parity(2)][d(2)][row(64)][256 ulls]
//   quantum = 2 ulls covering 4 hidden cols: ull = {2 bf16 payload (lo32) | seq (hi32)}
//   layer stride = 65536 ulls (512 KB); parity stride = 32768 ulls.

// ---------------- permuting cast: dst row d*2048 + col*4 + gate = src row d*2048 + gate*512 + col
__global__ void k_castWx(const float* __restrict__ src, unsigned short* __restrict__ dst, int K) {
    int np = blockIdx.x;               // 0..4095 dst row
    int dd = np >> 11, r = np & 2047;
    int g = r & 3, cj = r >> 2;
    const float* s = src + ((size_t)(dd * 2048 + g * 512 + cj)) * K;
    unsigned short* d = dst + (size_t)np * K;
    for (int e = threadIdx.x * 8; e < K; e += 128 * 8) {   // block = 128
        float4 a = *(const float4*)(s + e);
        float4 b = *(const float4*)(s + e + 4);
        ushort4 lo, hi;
        lo.x = f2bf(a.x); lo.y = f2bf(a.y); lo.z = f2bf(a.z); lo.w = f2bf(a.w);
        hi.x = f2bf(b.x); hi.y = f2bf(b.y); hi.z = f2bf(b.z); hi.w = f2bf(b.w);
        *(ushort4*)(d + e) = lo; *(ushort4*)(d + e + 4) = hi;
    }
}

// ---------------- embedding gather ----------------
__global__ void k_embed(const int* __restrict__ sent, const float* __restrict__ emb,
                        unsigned short* __restrict__ X0) {
    int row = blockIdx.x;              // t*64 + b
    int t = row >> 6, b = row & 63;
    int v = sent[b * kT + t];
    const float4* src = (const float4*)(emb + (size_t)v * 512);
    float4 f = src[threadIdx.x];       // block = 128
    ushort4 o;
    o.x = f2bf(f.x); o.y = f2bf(f.y); o.z = f2bf(f.z); o.w = f2bf(f.w);
    ((ushort4*)(X0 + (size_t)row * 512))[threadIdx.x] = o;
}

// ---------------- init: c states, fused biases, lw->bf16, seq-stamped h0 exchange ----------------
__global__ void k_init(const float* __restrict__ h0, const float* __restrict__ c0,
                       const float* __restrict__ bih0, const float* __restrict__ bhh0,
                       const float* __restrict__ bih1, const float* __restrict__ bhh1,
                       const float* __restrict__ lw,
                       unsigned long long* __restrict__ Xex, float* __restrict__ ccur,
                       float* __restrict__ biascat0, float* __restrict__ biascat1,
                       unsigned short* __restrict__ lwb) {
    int i = blockIdx.x * blockDim.x + threadIdx.x;
    const int NS = 4 * kB * kHD;       // 131072 c-state elems
    const int NX = 65536;              // parity-0 ulls across both layers
    if (i < NS) {
        ccur[i] = c0[i];
    } else if (i < NS + 8192) {
        int j2 = i - NS;
        int l = j2 >> 12;
        int n = j2 & 4095;             // src: d*2048 + g*512 + col
        int dd = n >> 11, r = n & 2047;
        int g = r >> 9, cj = r & 511;
        float v = l ? (bih1[n] + bhh1[n]) : (bih0[n] + bhh0[n]);
        int np = dd * 2048 + cj * 4 + g;   // gate-interleaved
        (l ? biascat1 : biascat0)[np] = v;
    } else if (i < NS + 8192 + 16384) {
        int idx = i - NS - 8192;
        lwb[idx] = f2bf(lw[idx]);
    } else if (i < NS + 8192 + 16384 + NX) {
        // parity-0: h0 payload stamped seq=0
        int u = i - (NS + 8192 + 16384);
        int l = u >> 15, rem = u & 32767;
        int d = rem >> 14, rem2 = rem & 16383;
        int b = rem2 >> 8, q2 = rem2 & 255;    // ull index within row (2 cols each)
        int j0 = q2 * 2;
        const float* hp = h0 + ((size_t)(l * 2 + d) * 64 + b) * 512 + j0;
        unsigned int pay = (unsigned)f2bf(hp[0]) | ((unsigned)f2bf(hp[1]) << 16);
        Xex[(size_t)l * 65536 + ((size_t)d * 64 + b) * 256 + q2] = (unsigned long long)pay;
    } else if (i < NS + 8192 + 16384 + 2 * NX) {
        // parity-1: invalidate (seq=0 < any odd step)
        int u = i - (NS + 8192 + 16384 + NX);
        int l = u >> 15, rem = u & 32767;
        Xex[(size_t)l * 65536 + 32768 + rem] = 0ull;
    }
}

// ---------------- standalone chunk GEMM (lead-in only) ----------------
__launch_bounds__(256, 2)
__global__ void k_gemm(const unsigned short* __restrict__ A,
                       const unsigned short* __restrict__ Bm,
                       const float* __restrict__ bias,
                       unsigned short* __restrict__ Cm,
                       int K, int afwd, int abwd) {
    const int nb = blockIdx.x & 31;
    const int mb = blockIdx.x >> 5;
    const int m0w = mb << 7;
    const int arow0 = (m0w < 2048) ? (afwd + m0w) : (abwd + (m0w - 2048));
    const int n0 = nb << 7;
    const int tid = threadIdx.x;
    const int lane = tid & 63;
    const int wave = tid >> 6;
    const int wm = wave >> 1, wn = wave & 1;
    const int l16 = lane & 15, quad = lane >> 4;
    __shared__ unsigned short As[128 * 32];
    __shared__ unsigned short Bs[128 * 32];
    const int srw = wave * 32 + (lane >> 2);
    const int sc  = lane & 3;
    unsigned short* AsW0 = As + wave * 1024;
    unsigned short* AsW1 = As + wave * 1024 + 512;
    unsigned short* BsW0 = Bs + wave * 1024;
    unsigned short* BsW1 = Bs + wave * 1024 + 512;

    f32x4 acc[4][4];
    #pragma unroll
    for (int i = 0; i < 4; ++i)
        #pragma unroll
        for (int jj = 0; jj < 4; ++jj) acc[i][jj] = (f32x4){0,0,0,0};

    const int kiters = K >> 5;
    for (int kk = 0; kk < kiters; ++kk) {
        __syncthreads();
        ld_lds16(A  + (size_t)(arow0 + srw)      * K + kk * 32 + sc * 8, AsW0);
        ld_lds16(A  + (size_t)(arow0 + srw + 16) * K + kk * 32 + sc * 8, AsW1);
        ld_lds16(Bm + (size_t)(n0 + srw)         * K + kk * 32 + sc * 8, BsW0);
        ld_lds16(Bm + (size_t)(n0 + srw + 16)    * K + kk * 32 + sc * 8, BsW1);
        __syncthreads();
        U16x8 af[4], bf[4];
        #pragma unroll
        for (int i = 0; i < 4; ++i) {
            af[i].u = *(const uint4*)(As + (wm * 64 + i * 16 + l16) * 32 + quad * 8);
            bf[i].u = *(const uint4*)(Bs + (wn * 64 + i * 16 + l16) * 32 + quad * 8);
        }
        #pragma unroll
        for (int i = 0; i < 4; ++i)
            #pragma unroll
            for (int jj = 0; jj < 4; ++jj)
                acc[i][jj] = __builtin_amdgcn_mfma_f32_16x16x32_bf16(af[i].v, bf[jj].v, acc[i][jj], 0, 0, 0);
    }
    #pragma unroll
    for (int jj = 0; jj < 4; ++jj) {
        int n = n0 + wn * 64 + jj * 16 + l16;
        float bv = bias[n];
        #pragma unroll
        for (int i = 0; i < 4; ++i) {
            int mrow = m0w + wm * 64 + i * 16 + quad * 4;
            #pragma unroll
            for (int rr = 0; rr < 4; ++rr)
                Cm[(size_t)(mrow + rr) * 4096 + n] = f2bf(acc[i][jj][rr] + bv);
        }
    }
}

// ---------------- fused: rec chunk (blocks 0..63) + next-chunk GEMM (blocks 64..255) ----
// rec step (seq-stamped one-hop exchange, 2 barriers, no flags/drains):
//   Gx prefetch -> retry-load 16 stamped ulls (wait stamp==s) -> zbuf -> BAR1 ->
//   MFMA -> wave-local gate transpose (lgkmcnt) -> activations -> hstash -> BAR2 ->
//   tid<256: store stamped h quanta (s+1) | tid>=256: hs/S output stores
__launch_bounds__(512, 1)
__global__ void k_fused(const unsigned short* __restrict__ Wh,   // [2][2048][512] bf16 PERMUTED
                        const unsigned short* __restrict__ Gx,    // rec input chunk
                        unsigned long long* __restrict__ Xex,     // layer's exchange buffer
                        float* __restrict__ cc,
                        unsigned short* __restrict__ hs,          // HS
                        unsigned short* __restrict__ S,
                        int s0, int split,
                        const unsigned short* __restrict__ Ag,    // gemm A
                        const unsigned short* __restrict__ Wxg,   // gemm B
                        const float* __restrict__ biasg,
                        unsigned short* __restrict__ Gxout,       // gemm out (other buffer)
                        int Kg, int gfwd, int gbwd, int do_gemm) {
    __shared__ __align__(16) char smem[52928];
    const int tid = threadIdx.x;

    if (blockIdx.x < 64) {
        // ================= recurrence =================
        unsigned short* zbuf   = (unsigned short*)smem;             // 32*520*2 = 33280 B
        float*          gsAll  = (float*)(smem + 33280);            // 8 waves * 544 f32 = 17408 B
        unsigned short* hstU16 = (unsigned short*)(smem + 50688);   // 8*35 ull padded = 2240 B
        unsigned long long* hU = (unsigned long long*)(smem + 50688);
        const int blk = blockIdx.x;
        const int d  = blk >> 5;
        const int bh = (blk >> 4) & 1;
        const int wc = blk & 15;
        const int wave = tid >> 6;
        const int lane = tid & 63;
        const int l16 = lane & 15;
        const int quad = lane >> 4;
        const int r4 = lane >> 2;          // 0..15: batch row within mt-tile
        const int u  = lane & 3;           // 0..3 : hidden unit within wave
        const int col = wc * 32 + wave * 4 + u;   // hidden col 0..511
        float* gw = gsAll + wave * 544;            // [2 mt][16 rows][17] f32
        const int r8 = tid >> 3, u8 = tid & 7;     // producer store mapping (tid<256)

        uint4 wreg[16];
        {
            const unsigned short* wrow =
                Wh + ((size_t)d * 2048 + wc * 128 + wave * 16 + l16) * 512 + quad * 8;
            #pragma unroll
            for (int kk = 0; kk < 16; ++kk) wreg[kk] = *(const uint4*)(wrow + kk * 32);
        }
        float cst[2];
        #pragma unroll
        for (int mt = 0; mt < 2; ++mt)
            cst[mt] = cc[((size_t)d * 64 + bh * 32 + mt * 16 + r4) * 512 + col];

        for (int sl = 0; sl < kL; ++sl) {
            const int s = s0 + sl;
            const int t = d ? (kT - 1 - s) : s;
            // Gx prefetch (independent of h -> issue before the exchange wait)
            ushort4 gx4[2];
            #pragma unroll
            for (int mt = 0; mt < 2; ++mt) {
                int b = bh * 32 + mt * 16 + r4;
                int grow = d ? (2048 + (kL - 1 - sl) * 64 + b) : (sl * 64 + b);
                gx4[mt] = *(const ushort4*)(Gx + (size_t)grow * 4096 + d * 2048 + col * 4);
            }
            // -------- seq-stamped exchange read: 8 quanta (16 ulls) per thread --------
            {
                const unsigned long long* xb =
                    Xex + ((size_t)((s & 1) * 2 + d) * 64 + bh * 32) * 256;
                const unsigned sq = (unsigned)s;
                unsigned long long va[8], vb[8];
                #pragma unroll
                for (int k = 0; k < 8; ++k) {
                    int idx = tid + k * 512;
                    int r = idx >> 7, q = idx & 127;
                    const unsigned long long* p = xb + r * 256 + q * 2;
                    va[k] = __hip_atomic_load(p,     __ATOMIC_RELAXED, __HIP_MEMORY_SCOPE_AGENT);
                    vb[k] = __hip_atomic_load(p + 1, __ATOMIC_RELAXED, __HIP_MEMORY_SCOPE_AGENT);
                }
                for (;;) {
                    int stale = 0;
                    #pragma unroll
                    for (int k = 0; k < 8; ++k) {
                        int idx = tid + k * 512;
                        int r = idx >> 7, q = idx & 127;
                        const unsigned long long* p = xb + r * 256 + q * 2;
                        if ((unsigned)(va[k] >> 32) < sq) {
                            va[k] = __hip_atomic_load(p, __ATOMIC_RELAXED, __HIP_MEMORY_SCOPE_AGENT);
                            stale = 1;
                        }
                        if ((unsigned)(vb[k] >> 32) < sq) {
                            vb[k] = __hip_atomic_load(p + 1, __ATOMIC_RELAXED, __HIP_MEMORY_SCOPE_AGENT);
                            stale = 1;
                        }
                    }
                    if (!stale) break;
                }
                #pragma unroll
                for (int k = 0; k < 8; ++k) {
                    int idx = tid + k * 512;
                    int r = idx >> 7, q = idx & 127;
                    unsigned long long pay = (va[k] & 0xffffffffull) | (vb[k] << 32);
                    *(unsigned long long*)(zbuf + r * 520 + q * 4) = pay;
                }
            }
            __syncthreads();                       // BAR1: zbuf complete
            f32x4 acc[2];
            acc[0] = (f32x4){0, 0, 0, 0};
            acc[1] = (f32x4){0, 0, 0, 0};
            #pragma unroll
            for (int kk = 0; kk < 16; ++kk) {
                U16x8 b; b.u = wreg[kk];
                #pragma unroll
                for (int mt = 0; mt < 2; ++mt) {
                    U16x8 a; a.u = *(const uint4*)(zbuf + (mt * 16 + l16) * 520 + kk * 32 + quad * 8);
                    acc[mt] = __builtin_amdgcn_mfma_f32_16x16x32_bf16(a.v, b.v, acc[mt], 0, 0, 0);
                }
            }
            // wave-local gate transpose: C[row=quad*4+rr][col=l16] -> (r4, u*4+g)
            #pragma unroll
            for (int mt = 0; mt < 2; ++mt)
                #pragma unroll
                for (int rr = 0; rr < 4; ++rr)
                    gw[mt * 272 + (quad * 4 + rr) * 17 + l16] = acc[mt][rr];
            asm volatile("s_waitcnt lgkmcnt(0)" ::: "memory");
            __builtin_amdgcn_sched_barrier(0);
            #pragma unroll
            for (int mt = 0; mt < 2; ++mt) {
                const float* gb = gw + mt * 272 + r4 * 17 + u * 4;
                float gi = gb[0] + bf2f(gx4[mt].x);
                float gf = gb[1] + bf2f(gx4[mt].y);
                float gg = gb[2] + bf2f(gx4[mt].z);
                float go = gb[3] + bf2f(gx4[mt].w);
                float si = fsig(gi);
                float sf = fsig(gf);
                float so = fsig(go);
                float tg = ftanh(gg);
                float cn = sf * cst[mt] + si * tg;
                cst[mt] = cn;
                float hn = so * ftanh(cn);
                // padded hstash: ull (wave,row) at hU[wave*35+row]
                hstU16[(wave * 35 + mt * 16 + r4) * 4 + u] = f2bf(hn);
            }
            __syncthreads();                       // BAR2: hstash complete
            if (tid < 256) {
                // stamped h quantum store: fire-and-forget, no drain, no flag
                unsigned long long hv = hU[u8 * 35 + r8];
                unsigned long long sq1 = (unsigned long long)(unsigned)(s + 1) << 32;
                unsigned long long A  = (hv & 0xffffffffull) | sq1;
                unsigned long long Bv = (hv >> 32) | sq1;
                unsigned long long* xw =
                    Xex + ((size_t)(((s + 1) & 1) * 2 + d) * 64 + bh * 32 + r8) * 256
                        + (wc * 8 + u8) * 2;
                __hip_atomic_store(xw,     A,  __ATOMIC_RELAXED, __HIP_MEMORY_SCOPE_AGENT);
                __hip_atomic_store(xw + 1, Bv, __ATOMIC_RELAXED, __HIP_MEMORY_SCOPE_AGENT);
            } else {
                // time-series output: off the inter-block critical path
                int q = tid - 256;                 // 0..255
                int r = q >> 3, uu = q & 7;
                unsigned long long val = hU[uu * 35 + r];
                int b = bh * 32 + r;
                bool toS = split && (d ? (t >= 256) : (t < 256));
                if (toS)
                    *(unsigned long long*)(S + ((size_t)t * 64 + b) * 512 + wc * 32 + uu * 4) = val;
                else
                    *(unsigned long long*)(hs + ((size_t)t * 64 + b) * 1024 + (size_t)d * 512 + wc * 32 + uu * 4) = val;
            }
        }
        #pragma unroll
        for (int mt = 0; mt < 2; ++mt)
            cc[((size_t)d * 64 + bh * 32 + mt * 16 + r4) * 512 + col] = cst[mt];
    } else {
        // ================= next-chunk GEMM =================
        if (!do_gemm) return;
        const int gw = blockIdx.x - 64;            // 0..191
        const int half = tid >> 8;                 // two 128x128 tiles per WG
        const int tid2 = tid & 255;
        const int w4 = tid2 >> 6;
        const int lane = tid2 & 63;
        const int l16 = lane & 15, quad = lane >> 4;
        unsigned short* As = (unsigned short*)(smem + half * 16384);
        unsigned short* Bs = (unsigned short*)(smem + half * 16384 + 8192);
        const int srw = w4 * 32 + (lane >> 2);
        const int sc  = lane & 3;
        const int wm = w4 >> 1, wn = w4 & 1;
        unsigned short* AsW0 = As + w4 * 1024;
        unsigned short* AsW1 = As + w4 * 1024 + 512;
        unsigned short* BsW0 = Bs + w4 * 1024;
        unsigned short* BsW1 = Bs + w4 * 1024 + 512;
        const int kiters = Kg >> 5;

        for (int pp = gw; pp < 512; pp += 192) {
            const int mb = pp >> 4;
            const int nb = ((pp & 15) << 1) + half;
            const int m0w = mb << 7;
            const int arow0 = (m0w < 2048) ? (gfwd + m0w) : (gbwd + (m0w - 2048));
            const int n0 = nb << 7;
            f32x4 acc[4][4];
            #pragma unroll
            for (int i = 0; i < 4; ++i)
                #pragma unroll
                for (int jj = 0; jj < 4; ++jj) acc[i][jj] = (f32x4){0,0,0,0};
            for (int kk = 0; kk < kiters; ++kk) {
                __syncthreads();               // both halves: same trip counts
                ld_lds16(Ag  + (size_t)(arow0 + srw)      * Kg + kk * 32 + sc * 8, AsW0);
                ld_lds16(Ag  + (size_t)(arow0 + srw + 16) * Kg + kk * 32 + sc * 8, AsW1);
                ld_lds16(Wxg + (size_t)(n0 + srw)         * Kg + kk * 32 + sc * 8, BsW0);
                ld_lds16(Wxg + (size_t)(n0 + srw + 16)    * Kg + kk * 32 + sc * 8, BsW1);
                __syncthreads();
                U16x8 af[4], bf[4];
                #pragma unroll
                for (int i = 0; i < 4; ++i) {
                    af[i].u = *(const uint4*)(As + (wm * 64 + i * 16 + l16) * 32 + quad * 8);
                    bf[i].u = *(const uint4*)(Bs + (wn * 64 + i * 16 + l16) * 32 + quad * 8);
                }
                #pragma unroll
                for (int i = 0; i < 4; ++i)
                    #pragma unroll
                    for (int jj = 0; jj < 4; ++jj)
                        acc[i][jj] = __builtin_amdgcn_mfma_f32_16x16x32_bf16(af[i].v, bf[jj].v, acc[i][jj], 0, 0, 0);
            }
            #pragma unroll
            for (int jj = 0; jj < 4; ++jj) {
                int n = n0 + wn * 64 + jj * 16 + l16;
                float bv = biasg[n];
                #pragma unroll
                for (int i = 0; i < 4; ++i) {
                    int mrow = m0w + wm * 64 + i * 16 + quad * 4;
                    #pragma unroll
                    for (int rr = 0; rr < 4; ++rr)
                        Gxout[(size_t)(mrow + rr) * 4096 + n] = f2bf(acc[i][jj][rr] + bv);
                }
            }
        }
    }
}

// ---------------- final linear, MFMA version ----------------
// grid = 512 (one block per t), block = 256 (4 waves x 16 rows). K=1024 over HS/S halves.
__global__ void k_linear(const unsigned short* __restrict__ hs1,
                         const unsigned short* __restrict__ S,
                         const unsigned short* __restrict__ lwb,   // [16][1024] bf16
                         const float* __restrict__ lb,
                         float* __restrict__ feats) {
    const int t = blockIdx.x;
    const int tid = threadIdx.x;
    const int wave = tid >> 6;
    const int lane = tid & 63;
    const int l16 = lane & 15, quad = lane >> 4;
    __shared__ unsigned short lws[16 * 1032];      // padded stride: 2-way LDS reads
    {
        #pragma unroll
        for (int i = 0; i < 8; ++i) {
            int idx = tid + i * 256;               // uint4 index over 16x1024 shorts
            int n = idx >> 7, c = idx & 127;
            *(uint4*)(lws + n * 1032 + c * 8) = *(const uint4*)(lwb + n * 1024 + c * 8);
        }
    }
    __syncthreads();
    const int brow = wave * 16 + l16;              // batch row this lane's A-frag covers
    f32x4 acc = {0, 0, 0, 0};
    #pragma unroll
    for (int kk = 0; kk < 32; ++kk) {
        int k0 = kk * 32 + quad * 8;
        const unsigned short* p;
        if (kk < 16)   // fwd half: S if t<256 else HS
            p = (t < 256) ? S   + ((size_t)t * 64 + brow) * 512  + k0
                          : hs1 + ((size_t)t * 64 + brow) * 1024 + k0;
        else           // bwd half: S if t>=256 else HS
            p = (t >= 256) ? S   + ((size_t)t * 64 + brow) * 512  + (k0 - 512)
                           : hs1 + ((size_t)t * 64 + brow) * 1024 + k0;
        U16x8 a; a.u = *(const uint4*)p;
        U16x8 b; b.u = *(const uint4*)(lws + l16 * 1032 + k0);
        acc = __builtin_amdgcn_mfma_f32_16x16x32_bf16(a.v, b.v, acc, 0, 0, 0);
    }
    // C[m=quad*4+rr][n=l16]; m -> batch row, n -> class
    float bv = lb[l16];
    #pragma unroll
    for (int rr = 0; rr < 4; ++rr) {
        int b = wave * 16 + quad * 4 + rr;
        feats[(size_t)b * (kT * kC) + t * kC + l16] = acc[rr] + bv;
    }
}

// ---------------- Viterbi ----------------
__global__ void k_viterbi(const float* __restrict__ feats, const float* __restrict__ trans,
                          float* __restrict__ out) {
    int b = blockIdx.x;
    int lane = threadIdx.x;            // block = 64
    __shared__ unsigned char bp[kT * kC];
    __shared__ float fv[2][kC];
    __shared__ float tbuf[kC];
    float trow[16];
    float tstop = 0.f;
    if (lane < 16) {
        #pragma unroll
        for (int p = 0; p < 16; ++p) trow[p] = trans[lane * 16 + p];
        tstop = trans[kSTOP * 16 + lane];
        fv[0][lane] = (lane == kSTART) ? 0.f : NEGV;
    }
    __syncthreads();
    const float* fb = feats + (size_t)b * (kT * kC);
    for (int t = 0; t < kT; ++t) {
        if (lane < 16) {
            float m = -3.4e38f; int arg = 0;
            #pragma unroll
            for (int p = 0; p < 16; ++p) {
                float v = fv[t & 1][p] + trow[p];
                if (v > m) { m = v; arg = p; }   // strict >: first max = jnp.argmax
            }
            bp[t * 16 + lane] = (unsigned char)arg;
            fv[(t + 1) & 1][lane] = m + fb[t * 16 + lane];
        }
        __syncthreads();
    }
    if (lane < 16) tbuf[lane] = fv[kT & 1][lane] + tstop;
    __syncthreads();
    if (lane == 0) {
        float bm = tbuf[0]; int best = 0;
        #pragma unroll
        for (int p = 1; p < 16; ++p) if (tbuf[p] > bm) { bm = tbuf[p]; best = p; }
        out[b] = bm;
        float* path = out + kB + (size_t)b * kT;
        int tag = best;
        for (int t = kT - 1; t >= 0; --t) {
            path[t] = (float)tag;
            tag = bp[t * 16 + tag];
        }
    }
}

// ---------------- host ----------------
extern "C" void kernel_launch(void* const* d_in, const int* in_sizes, int n_in,
                              void* d_out, int out_size, void* d_ws, size_t ws_size,
                              hipStream_t stream) {
    const int*   sent = (const int*)d_in[0];
    const float* emb  = (const float*)d_in[1];
    const float* wih0 = (const float*)d_in[2];
    const float* whh0 = (const float*)d_in[3];
    const float* bih0 = (const float*)d_in[4];
    const float* bhh0 = (const float*)d_in[5];
    const float* wih1 = (const float*)d_in[6];
    const float* whh1 = (const float*)d_in[7];
    const float* bih1 = (const float*)d_in[8];
    const float* bhh1 = (const float*)d_in[9];
    const float* lw   = (const float*)d_in[10];
    const float* lb   = (const float*)d_in[11];
    const float* tr   = (const float*)d_in[12];
    const float* h0   = (const float*)d_in[13];
    const float* c0   = (const float*)d_in[14];
    float* out = (float*)d_out;

    char* ws = (char*)d_ws;
    size_t off = 0;
    auto alloc = [&](size_t bytes) -> void* {
        void* p = ws + off; off += (bytes + 255) & ~(size_t)255; return p;
    };
    // X0 (32MB) + Wx0 dead during layer-1 recurrence; S aliases X0.
    unsigned short* X0    = (unsigned short*)alloc((size_t)kT * kB * 512 * 2);       // 33.5MB
    unsigned short* Wx0   = (unsigned short*)alloc((size_t)4096 * 512 * 2);          // 4MB
    unsigned short* S     = (unsigned short*)X0;                                     // alias
    unsigned short* Wh0   = (unsigned short*)alloc((size_t)4096 * 512 * 2);          // 4MB
    unsigned short* Wx1   = (unsigned short*)alloc((size_t)4096 * 1024 * 2);         // 8MB
    unsigned short* Wh1   = (unsigned short*)alloc((size_t)4096 * 512 * 2);          // 4MB
    float*          biascat0 = (float*)alloc(4096 * 4);
    float*          biascat1 = (float*)alloc(4096 * 4);
    unsigned short* HS    = (unsigned short*)alloc((size_t)kT * kB * 1024 * 2);      // 67MB
    unsigned long long* Xex = (unsigned long long*)alloc((size_t)2 * 65536 * 8);     // 1MB exchange
    float*          ccur  = (float*)alloc((size_t)4 * kB * kHD * 4);
    float*          feats = (float*)alloc((size_t)kB * kT * kC * 4);
    unsigned short* lwb   = (unsigned short*)alloc(16384 * 2);
    unsigned short* Gx0   = (unsigned short*)alloc((size_t)4096 * 4096 * 2);         // 33.5MB
    unsigned short* Gx1   = (unsigned short*)alloc((size_t)4096 * 4096 * 2);         // 33.5MB
    unsigned short* GxB[2] = {Gx0, Gx1};

    k_castWx<<<4096, 128, 0, stream>>>(wih0, Wx0, 512);
    k_castWx<<<4096, 128, 0, stream>>>(whh0, Wh0, 512);
    k_castWx<<<4096, 128, 0, stream>>>(wih1, Wx1, 1024);
    k_castWx<<<4096, 128, 0, stream>>>(whh1, Wh1, 512);
    // items: ccur 131072 + biascat 8192 + lwb 16384 + Xex parity0 65536 + parity1 65536
    k_init<<<(131072 + 8192 + 16384 + 2 * 65536) / 256, 256, 0, stream>>>(
        h0, c0, bih0, bhh0, bih1, bhh1, lw, Xex, ccur, biascat0, biascat1, lwb);
    k_embed<<<kT * kB, 128, 0, stream>>>(sent, emb, X0);

    unsigned long long* Xex1 = Xex + (size_t)65536;
    float*              ccur1 = ccur + (size_t)65536;

    // layer 0: lead-in GEMM, then fused rec(ch)+gemm(ch+1)
    k_gemm<<<1024, 256, 0, stream>>>(X0, Wx0, biascat0, Gx0, 512, 0, (kT - kL) * 64);
    for (int ch = 0; ch < 16; ++ch) {
        int s0n = (ch + 1) * kL;
        k_fused<<<256, 512, 0, stream>>>(Wh0, GxB[ch & 1], Xex, ccur, HS, S, ch * kL, 0,
                                         X0, Wx0, biascat0, GxB[(ch + 1) & 1], 512,
                                         s0n * 64, (kT - kL - s0n) * 64, ch < 15);
    }
    // layer 1: lead-in GEMM (after l0 fully done), then fused
    k_gemm<<<1024, 256, 0, stream>>>(HS, Wx1, biascat1, Gx0, 1024, 0, (kT - kL) * 64);
    for (int ch = 0; ch < 16; ++ch) {
        int s0n = (ch + 1) * kL;
        k_fused<<<256, 512, 0, stream>>>(Wh1, GxB[ch & 1], Xex1, ccur1, HS, S, ch * kL, 1,
                                         HS, Wx1, biascat1, GxB[(ch + 1) & 1], 1024,
                                         s0n * 64, (kT - kL - s0n) * 64, ch < 15);
    }

    k_linear<<<kT, 256, 0, stream>>>(HS, S, lwb, lb, feats);
    k_viterbi<<<kB, 64, 0, stream>>>(feats, tr, out);
}